// Round 1
// baseline (913.645 us; speedup 1.0000x reference)
//
#include <hip/hip_runtime.h>
#include <hip/hip_bf16.h>

#define BB 256
#define TT 512
#define EE 300
#define H1N 50
#define H2N 10
#define G4 200     // 4*H1
#define JP 256     // padded gate dim for Wt

// ---------------------------------------------------------------------------
// K1: transpose + zero-pad W_ih1 [200,300] -> Wt [300][256]
__global__ void wtrans_kernel(const float* __restrict__ W, float* __restrict__ Wt) {
    int e = blockIdx.x;        // 0..299
    int j = threadIdx.x;       // 0..255
    Wt[e * JP + j] = (j < G4) ? W[j * EE + e] : 0.f;
}

// ---------------------------------------------------------------------------
// K2: G1[bb][t][j] = b1[j] + emb[x[b][t]] . W_ih1[j]   (only where t-tile < len)
__device__ __forceinline__ float f4get(const float4& v, int u) {
    return u == 0 ? v.x : u == 1 ? v.y : u == 2 ? v.z : v.w;
}

__global__ __launch_bounds__(256) void proj_kernel(
    const int* __restrict__ x, const int* __restrict__ lengths,
    const float* __restrict__ emb, const float* __restrict__ b1,
    const float* __restrict__ Wt, float* __restrict__ G1, int b0)
{
    const int b  = b0 + blockIdx.y;
    const int t0 = blockIdx.x * 32;
    const int len = lengths[b];
    if (t0 >= len) return;                       // whole tile is padding: dead

    const int tid = threadIdx.x;
    const int rg  = tid >> 5;                    // 0..7 : rows rg*4 .. rg*4+3
    const int jg  = tid & 31;                    // j = jg*8 .. jg*8+7 (valid if jg<25)

    const float* er[4];
    #pragma unroll
    for (int q = 0; q < 4; ++q) {
        int t = t0 + rg * 4 + q;
        er[q] = emb + (size_t)x[b * TT + t] * EE;
    }

    float acc[4][8];
    {
        float bv[8];
        if (jg < 25) {
            float4 u0 = *(const float4*)(b1 + (jg << 3));
            float4 u1 = *(const float4*)(b1 + (jg << 3) + 4);
            bv[0]=u0.x; bv[1]=u0.y; bv[2]=u0.z; bv[3]=u0.w;
            bv[4]=u1.x; bv[5]=u1.y; bv[6]=u1.z; bv[7]=u1.w;
        } else {
            #pragma unroll
            for (int k = 0; k < 8; ++k) bv[k] = 0.f;
        }
        #pragma unroll
        for (int q = 0; q < 4; ++q)
            #pragma unroll
            for (int k = 0; k < 8; ++k) acc[q][k] = bv[k];
    }

    #pragma unroll 2
    for (int e = 0; e < EE; e += 4) {
        float4 av[4];
        #pragma unroll
        for (int q = 0; q < 4; ++q) av[q] = *(const float4*)(er[q] + e);
        #pragma unroll
        for (int u = 0; u < 4; ++u) {
            const float* wrow = Wt + (size_t)(e + u) * JP + (jg << 3);
            float4 w0 = *(const float4*)(wrow);
            float4 w1 = *(const float4*)(wrow + 4);
            #pragma unroll
            for (int q = 0; q < 4; ++q) {
                float a = f4get(av[q], u);
                acc[q][0] = fmaf(a, w0.x, acc[q][0]);
                acc[q][1] = fmaf(a, w0.y, acc[q][1]);
                acc[q][2] = fmaf(a, w0.z, acc[q][2]);
                acc[q][3] = fmaf(a, w0.w, acc[q][3]);
                acc[q][4] = fmaf(a, w1.x, acc[q][4]);
                acc[q][5] = fmaf(a, w1.y, acc[q][5]);
                acc[q][6] = fmaf(a, w1.z, acc[q][6]);
                acc[q][7] = fmaf(a, w1.w, acc[q][7]);
            }
        }
    }

    if (jg < 25) {
        float* gbase = G1 + ((size_t)blockIdx.y * TT + t0) * G4 + (jg << 3);
        #pragma unroll
        for (int q = 0; q < 4; ++q) {
            float* gp = gbase + (size_t)(rg * 4 + q) * G4;
            *(float4*)(gp)     = make_float4(acc[q][0], acc[q][1], acc[q][2], acc[q][3]);
            *(float4*)(gp + 4) = make_float4(acc[q][4], acc[q][5], acc[q][6], acc[q][7]);
        }
    }
}

// ---------------------------------------------------------------------------
// K3: recurrent part. One block per batch element, runs len[b] steps.
__device__ __forceinline__ float sigm(float x) {
    return __builtin_amdgcn_rcpf(1.f + __builtin_amdgcn_exp2f(-1.442695040888963f * x));
}
__device__ __forceinline__ float tanh_(float x) {
    float t = __builtin_amdgcn_exp2f(2.885390081777927f * x);   // e^(2x)
    return 1.f - 2.f * __builtin_amdgcn_rcpf(t + 1.f);
}

__global__ __launch_bounds__(256) void lstm_kernel(
    const int* __restrict__ lengths,
    const float* __restrict__ W_hh1, const float* __restrict__ W_ih2,
    const float* __restrict__ W_hh2, const float* __restrict__ b2,
    const float* __restrict__ fc1w, const float* __restrict__ fc1b,
    const float* __restrict__ fc2w, const float* __restrict__ fc2b,
    const float* __restrict__ G1, float* __restrict__ out, int b0)
{
    const int bb  = blockIdx.x;
    const int b   = b0 + bb;
    const int tid = threadIdx.x;
    const int len = lengths[b];

    __shared__ __align__(16) float h1s[52];
    __shared__ __align__(16) float h2s[12];
    __shared__ float g1buf[200];
    __shared__ float g2buf[40];
    __shared__ float zbuf[16];

    // per-thread weight registers: tid<200 -> W_hh1 row; tid in [200,240) -> W_ih2|W_hh2 row
    float wreg[60];
    #pragma unroll
    for (int e = 0; e < 60; ++e) wreg[e] = 0.f;
    if (tid < 200) {
        const float* wp = W_hh1 + tid * H1N;
        #pragma unroll
        for (int e = 0; e < 50; ++e) wreg[e] = wp[e];
    } else if (tid < 240) {
        const float* wp = W_ih2 + (tid - 200) * H1N;
        #pragma unroll
        for (int e = 0; e < 50; ++e) wreg[e] = wp[e];
        const float* wp2 = W_hh2 + (tid - 200) * H2N;
        #pragma unroll
        for (int e = 0; e < 10; ++e) wreg[50 + e] = wp2[e];
    }
    const float b2r = (tid >= 200 && tid < 240) ? b2[tid - 200] : 0.f;

    float c1 = 0.f, c2 = 0.f;
    if (tid < 52) h1s[tid] = 0.f;
    if (tid < 12) h2s[tid] = 0.f;
    __syncthreads();

    const float* g1p = G1 + (size_t)bb * TT * G4;
    float gnext = (tid < 200) ? g1p[tid] : 0.f;     // row t=0

    for (int t = 0; t < len; ++t) {
        // ---- phase 1: gates1 = G1[t] + W_hh1 . h1  (threads 0..199)
        if (tid < 200) {
            float g = gnext;
            int tn = (t + 1 < len) ? t + 1 : t;
            gnext = g1p[(size_t)tn * G4 + tid];      // prefetch next row
            float s0 = 0.f, s1 = 0.f, s2 = 0.f, s3 = 0.f;
            #pragma unroll
            for (int m = 0; m < 13; ++m) {           // h1s[50..51] = 0 pad
                float4 hv = *(const float4*)(h1s + m * 4);
                s0 = fmaf(wreg[4*m+0], hv.x, s0);
                s1 = fmaf(wreg[4*m+1], hv.y, s1);
                s2 = fmaf(wreg[4*m+2], hv.z, s2);
                s3 = fmaf(wreg[4*m+3], hv.w, s3);
            }
            g1buf[tid] = g + (s0 + s1) + (s2 + s3);
        }
        __syncthreads();
        // ---- phase 2: LSTM1 cell update (threads 0..49)
        if (tid < H1N) {
            float gi = g1buf[tid], gf = g1buf[tid + 50];
            float gg = g1buf[tid + 100], go = g1buf[tid + 150];
            float cn = sigm(gf) * c1 + sigm(gi) * tanh_(gg);
            c1 = cn;
            h1s[tid] = sigm(go) * tanh_(cn);
        }
        __syncthreads();
        // ---- phase 3: gates2 = b2 + W_ih2 . h1new + W_hh2 . h2  (threads 200..239)
        if (tid >= 200 && tid < 240) {
            float s0 = 0.f, s1 = 0.f, s2 = 0.f, s3 = 0.f;
            #pragma unroll
            for (int m = 0; m < 13; ++m) {           // wreg[50..51]*h1s[50..51]=0: safe
                float4 hv = *(const float4*)(h1s + m * 4);
                s0 = fmaf(wreg[4*m+0], hv.x, s0);
                s1 = fmaf(wreg[4*m+1], hv.y, s1);
                s2 = fmaf(wreg[4*m+2], hv.z, s2);
                s3 = fmaf(wreg[4*m+3], hv.w, s3);
            }
            float s4 = 0.f;
            #pragma unroll
            for (int e = 0; e < 10; ++e) s4 = fmaf(wreg[50 + e], h2s[e], s4);
            g2buf[tid - 200] = b2r + (s0 + s1) + (s2 + s3) + s4;
        }
        __syncthreads();
        // ---- phase 4: LSTM2 cell update (threads 0..9)
        if (tid < H2N) {
            float gi = g2buf[tid], gf = g2buf[tid + 10];
            float gg = g2buf[tid + 20], go = g2buf[tid + 30];
            float cn = sigm(gf) * c2 + sigm(gi) * tanh_(gg);
            c2 = cn;
            h2s[tid] = sigm(go) * tanh_(cn);
        }
        __syncthreads();
    }

    // ---- MLP head: z = relu(fc1 h2 + fc1b); out = fc2 z + fc2b
    if (tid < 10) {
        float s = fc1b[tid];
        #pragma unroll
        for (int e = 0; e < 10; ++e) s = fmaf(fc1w[tid * 10 + e], h2s[e], s);
        zbuf[tid] = s > 0.f ? s : 0.f;
    }
    __syncthreads();
    if (tid == 0) {
        float s = fc2b[0];
        #pragma unroll
        for (int e = 0; e < 10; ++e) s = fmaf(fc2w[e], zbuf[e], s);
        out[b] = s;
    }
}

// ---------------------------------------------------------------------------
extern "C" void kernel_launch(void* const* d_in, const int* in_sizes, int n_in,
                              void* d_out, int out_size, void* d_ws, size_t ws_size,
                              hipStream_t stream)
{
    const int*   x     = (const int*)  d_in[0];
    const int*   len   = (const int*)  d_in[1];
    const float* emb   = (const float*)d_in[2];
    const float* W_ih1 = (const float*)d_in[3];
    const float* W_hh1 = (const float*)d_in[4];
    const float* b1    = (const float*)d_in[5];
    const float* W_ih2 = (const float*)d_in[6];
    const float* W_hh2 = (const float*)d_in[7];
    const float* b2    = (const float*)d_in[8];
    const float* fc1w  = (const float*)d_in[9];
    const float* fc1b  = (const float*)d_in[10];
    const float* fc2w  = (const float*)d_in[11];
    const float* fc2b  = (const float*)d_in[12];
    float* out = (float*)d_out;

    const size_t wt_bytes = (size_t)EE * JP * sizeof(float);     // 307200
    const size_t per_b    = (size_t)TT * G4 * sizeof(float);     // 409600
    float* Wt = (float*)d_ws;
    float* G1 = (float*)((char*)d_ws + wt_bytes);

    size_t avail = ws_size > wt_bytes ? ws_size - wt_bytes : 0;
    int chunk = (int)(avail / per_b);
    if (chunk < 1) chunk = 1;          // (requires ~717KB of ws; chunked if less than full)
    if (chunk > BB) chunk = BB;

    wtrans_kernel<<<dim3(EE), dim3(256), 0, stream>>>(W_ih1, Wt);

    for (int b0 = 0; b0 < BB; b0 += chunk) {
        int nb = (BB - b0) < chunk ? (BB - b0) : chunk;
        proj_kernel<<<dim3(TT / 32, nb), dim3(256), 0, stream>>>(
            x, len, emb, b1, Wt, G1, b0);
        lstm_kernel<<<dim3(nb), dim3(256), 0, stream>>>(
            len, W_hh1, W_ih2, W_hh2, b2, fc1w, fc1b, fc2w, fc2b, G1, out, b0);
    }
}

// Round 2
// 681.212 us; speedup vs baseline: 1.3412x; 1.3412x over previous
//
#include <hip/hip_runtime.h>
#include <hip/hip_bf16.h>

#define BB 256
#define TT 512
#define EE 300
#define G4 200     // 4*H1
#define JP 256     // padded gate dim for Wt

// permuted gate row: LDS/G1 column jp corresponds to W row (jp&3)*50 + (jp>>2)
// so that thread tid==jp has gates (i,f,g,o) of unit u=tid>>2 in its lane quad.

__device__ __forceinline__ float sigm(float x) {
    return __builtin_amdgcn_rcpf(1.f + __builtin_amdgcn_exp2f(-1.442695040888963f * x));
}
__device__ __forceinline__ float tanh_(float x) {
    float t = __builtin_amdgcn_exp2f(2.885390081777927f * x);   // e^(2x)
    return 1.f - 2.f * __builtin_amdgcn_rcpf(t + 1.f);
}

// ---------------------------------------------------------------------------
// K1: permuted transpose + zero-pad W_ih1 [200,300] -> Wt [300][256]
__global__ void wtrans_kernel(const float* __restrict__ W, float* __restrict__ Wt) {
    int e = blockIdx.x;        // 0..299
    int j = threadIdx.x;       // 0..255
    float v = 0.f;
    if (j < G4) {
        int row = (j & 3) * 50 + (j >> 2);
        v = W[row * EE + e];
    }
    Wt[e * JP + j] = v;
}

// ---------------------------------------------------------------------------
// K2: G1[bb][t][jp] = b1[row(jp)] + emb[x[b][t]] . W_ih1[row(jp)]
__device__ __forceinline__ float f4get(const float4& v, int u) {
    return u == 0 ? v.x : u == 1 ? v.y : u == 2 ? v.z : v.w;
}

__global__ __launch_bounds__(256) void proj_kernel(
    const int* __restrict__ x, const int* __restrict__ lengths,
    const float* __restrict__ emb, const float* __restrict__ b1,
    const float* __restrict__ Wt, float* __restrict__ G1, int b0)
{
    const int b  = b0 + blockIdx.y;
    const int t0 = blockIdx.x * 64;
    const int len = lengths[b];
    if (t0 >= len) return;                       // whole tile is padding: dead

    const int tid = threadIdx.x;
    const int rg  = tid >> 5;                    // 0..7 : rows rg*8 .. rg*8+7
    const int jg  = tid & 31;                    // cols jg*8..jg*8+7, valid if jg<25
    if (jg >= 25) return;

    const float* er[8];
    #pragma unroll
    for (int q = 0; q < 8; ++q) {
        int t = t0 + rg * 8 + q;
        er[q] = emb + (size_t)x[b * TT + t] * EE;
    }

    float acc[8][8];
    {
        float bv[8];
        #pragma unroll
        for (int k = 0; k < 8; ++k) {
            int jp = (jg << 3) + k;
            bv[k] = b1[(jp & 3) * 50 + (jp >> 2)];
        }
        #pragma unroll
        for (int q = 0; q < 8; ++q)
            #pragma unroll
            for (int k = 0; k < 8; ++k) acc[q][k] = bv[k];
    }

    for (int e = 0; e < EE; e += 4) {
        float4 av[8];
        #pragma unroll
        for (int q = 0; q < 8; ++q) av[q] = *(const float4*)(er[q] + e);
        #pragma unroll
        for (int u = 0; u < 4; ++u) {
            const float* wrow = Wt + (size_t)(e + u) * JP + (jg << 3);
            float4 w0 = *(const float4*)(wrow);
            float4 w1 = *(const float4*)(wrow + 4);
            #pragma unroll
            for (int q = 0; q < 8; ++q) {
                float a = f4get(av[q], u);
                acc[q][0] = fmaf(a, w0.x, acc[q][0]);
                acc[q][1] = fmaf(a, w0.y, acc[q][1]);
                acc[q][2] = fmaf(a, w0.z, acc[q][2]);
                acc[q][3] = fmaf(a, w0.w, acc[q][3]);
                acc[q][4] = fmaf(a, w1.x, acc[q][4]);
                acc[q][5] = fmaf(a, w1.y, acc[q][5]);
                acc[q][6] = fmaf(a, w1.z, acc[q][6]);
                acc[q][7] = fmaf(a, w1.w, acc[q][7]);
            }
        }
    }

    float* gbase = G1 + ((size_t)blockIdx.y * TT + t0) * G4 + (jg << 3);
    #pragma unroll
    for (int q = 0; q < 8; ++q) {
        float* gp = gbase + (size_t)(rg * 8 + q) * G4;
        *(float4*)(gp)     = make_float4(acc[q][0], acc[q][1], acc[q][2], acc[q][3]);
        *(float4*)(gp + 4) = make_float4(acc[q][4], acc[q][5], acc[q][6], acc[q][7]);
    }
}

// ---------------------------------------------------------------------------
// K3: recurrence. One block (320 thr) per batch element, 1 barrier per step.
// tid 0..199   : LSTM1 row (tid&3)*50+(tid>>2)  (waves 0..3, quad = unit)
// tid 256..295 : LSTM2 row (q&3)*10+(q>>2), q=tid-256 (wave 4), lags 1 step
__global__ __launch_bounds__(320) void lstm_kernel(
    const int* __restrict__ lengths,
    const float* __restrict__ W_hh1, const float* __restrict__ W_ih2,
    const float* __restrict__ W_hh2, const float* __restrict__ b2,
    const float* __restrict__ fc1w, const float* __restrict__ fc1b,
    const float* __restrict__ fc2w, const float* __restrict__ fc2b,
    const float* __restrict__ G1, float* __restrict__ out, int b0)
{
    const int bb  = blockIdx.x;
    const int b   = b0 + bb;
    const int tid = threadIdx.x;
    const int len = lengths[b];
    const int lane = tid & 63;
    const int ql   = lane & ~3;

    __shared__ __align__(16) float h1s[2][52];
    __shared__ __align__(16) float h2s[2][12];
    __shared__ __align__(16) float hfin[12];
    __shared__ float zbuf[10];

    if (tid < 52) { h1s[0][tid] = 0.f; h1s[1][tid] = 0.f; }
    if (tid < 12) { h2s[0][tid] = 0.f; h2s[1][tid] = 0.f; }

    const bool is1 = (tid < 200);
    const bool is2 = (tid >= 256 && tid < 296);

    float wreg[52];                 // LSTM1: W_hh1 row | LSTM2: W_ih2 row
    float wregb[12];                // LSTM2: W_hh2 row
    #pragma unroll
    for (int k = 0; k < 52; ++k) wreg[k] = 0.f;
    #pragma unroll
    for (int k = 0; k < 12; ++k) wregb[k] = 0.f;
    float b2r = 0.f;

    if (is1) {
        int u = tid >> 2, g = tid & 3;
        const float* wp = W_hh1 + (g * 50 + u) * 50;
        #pragma unroll
        for (int k = 0; k < 50; ++k) wreg[k] = wp[k];
    } else if (is2) {
        int q = tid - 256, u = q >> 2, g = q & 3;
        int row = g * 10 + u;
        const float* wp = W_ih2 + row * 50;
        #pragma unroll
        for (int k = 0; k < 50; ++k) wreg[k] = wp[k];
        const float* wp2 = W_hh2 + row * 10;
        #pragma unroll
        for (int k = 0; k < 10; ++k) wregb[k] = wp2[k];
        b2r = b2[row];
    }

    float h1v[52], h2v[12];
    #pragma unroll
    for (int k = 0; k < 52; ++k) h1v[k] = 0.f;
    #pragma unroll
    for (int k = 0; k < 12; ++k) h2v[k] = 0.f;

    float c1 = 0.f, c2 = 0.f;
    const float* g1p = G1 + (size_t)bb * TT * G4;
    float gcur = is1 ? g1p[tid] : 0.f;            // row t=0

    __syncthreads();                               // LDS zero-init visible

    for (int i = 0; i < len; ++i) {
        if (is1) {
            float g = gcur;
            int tn = (i + 1 < len) ? i + 1 : i;
            gcur = g1p[(size_t)tn * G4 + tid];      // prefetch next row
            float s0 = 0.f, s1 = 0.f, s2 = 0.f, s3 = 0.f;
            #pragma unroll
            for (int m = 0; m < 13; ++m) {
                s0 = fmaf(wreg[4*m+0], h1v[4*m+0], s0);
                s1 = fmaf(wreg[4*m+1], h1v[4*m+1], s1);
                s2 = fmaf(wreg[4*m+2], h1v[4*m+2], s2);
                s3 = fmaf(wreg[4*m+3], h1v[4*m+3], s3);
            }
            float gv = g + (s0 + s1) + (s2 + s3);
            float gi = __shfl(gv, ql + 0, 64);
            float gf = __shfl(gv, ql + 1, 64);
            float gg = __shfl(gv, ql + 2, 64);
            float go = __shfl(gv, ql + 3, 64);
            float cn = sigm(gf) * c1 + sigm(gi) * tanh_(gg);
            c1 = cn;
            float hn = sigm(go) * tanh_(cn);
            if ((tid & 3) == 0) h1s[i & 1][tid >> 2] = hn;
        } else if (is2 && i >= 1) {
            float s0 = 0.f, s1 = 0.f, s2 = 0.f, s3 = 0.f;
            #pragma unroll
            for (int m = 0; m < 13; ++m) {
                s0 = fmaf(wreg[4*m+0], h1v[4*m+0], s0);
                s1 = fmaf(wreg[4*m+1], h1v[4*m+1], s1);
                s2 = fmaf(wreg[4*m+2], h1v[4*m+2], s2);
                s3 = fmaf(wreg[4*m+3], h1v[4*m+3], s3);
            }
            #pragma unroll
            for (int m = 0; m < 3; ++m) {
                s0 = fmaf(wregb[4*m+0], h2v[4*m+0], s0);
                s1 = fmaf(wregb[4*m+1], h2v[4*m+1], s1);
                s2 = fmaf(wregb[4*m+2], h2v[4*m+2], s2);
                s3 = fmaf(wregb[4*m+3], h2v[4*m+3], s3);
            }
            float gv = b2r + (s0 + s1) + (s2 + s3);
            float gi = __shfl(gv, ql + 0, 64);
            float gf = __shfl(gv, ql + 1, 64);
            float gg = __shfl(gv, ql + 2, 64);
            float go = __shfl(gv, ql + 3, 64);
            float cn = sigm(gf) * c2 + sigm(gi) * tanh_(gg);
            c2 = cn;
            float hn = sigm(go) * tanh_(cn);
            if ((tid & 3) == 0) h2s[i & 1][(tid - 256) >> 2] = hn;
        }
        __syncthreads();
        // reload h(i) for next iteration (regs), from buffer written this iter
        {
            const float* hb = h1s[i & 1];
            #pragma unroll
            for (int m = 0; m < 13; ++m) {
                float4 v = *(const float4*)(hb + 4 * m);
                h1v[4*m+0] = v.x; h1v[4*m+1] = v.y;
                h1v[4*m+2] = v.z; h1v[4*m+3] = v.w;
            }
            const float* hb2 = h2s[i & 1];
            #pragma unroll
            for (int m = 0; m < 3; ++m) {
                float4 v = *(const float4*)(hb2 + 4 * m);
                h2v[4*m+0] = v.x; h2v[4*m+1] = v.y;
                h2v[4*m+2] = v.z; h2v[4*m+3] = v.w;
            }
        }
    }

    // ---- tail: h2(len-1) from h1(len-1), h2(len-2)
    if (is2) {
        float s0 = 0.f, s1 = 0.f, s2 = 0.f, s3 = 0.f;
        #pragma unroll
        for (int m = 0; m < 13; ++m) {
            s0 = fmaf(wreg[4*m+0], h1v[4*m+0], s0);
            s1 = fmaf(wreg[4*m+1], h1v[4*m+1], s1);
            s2 = fmaf(wreg[4*m+2], h1v[4*m+2], s2);
            s3 = fmaf(wreg[4*m+3], h1v[4*m+3], s3);
        }
        #pragma unroll
        for (int m = 0; m < 3; ++m) {
            s0 = fmaf(wregb[4*m+0], h2v[4*m+0], s0);
            s1 = fmaf(wregb[4*m+1], h2v[4*m+1], s1);
            s2 = fmaf(wregb[4*m+2], h2v[4*m+2], s2);
            s3 = fmaf(wregb[4*m+3], h2v[4*m+3], s3);
        }
        float gv = b2r + (s0 + s1) + (s2 + s3);
        float gi = __shfl(gv, ql + 0, 64);
        float gf = __shfl(gv, ql + 1, 64);
        float gg = __shfl(gv, ql + 2, 64);
        float go = __shfl(gv, ql + 3, 64);
        float cn = sigm(gf) * c2 + sigm(gi) * tanh_(gg);
        float hn = sigm(go) * tanh_(cn);
        if ((tid & 3) == 0) hfin[(tid - 256) >> 2] = hn;
    }
    __syncthreads();

    // ---- MLP head
    if (tid < 10) {
        float s = fc1b[tid];
        #pragma unroll
        for (int e = 0; e < 10; ++e) s = fmaf(fc1w[tid * 10 + e], hfin[e], s);
        zbuf[tid] = s > 0.f ? s : 0.f;
    }
    __syncthreads();
    if (tid == 0) {
        float s = fc2b[0];
        #pragma unroll
        for (int e = 0; e < 10; ++e) s = fmaf(fc2w[e], zbuf[e], s);
        out[b] = s;
    }
}

// ---------------------------------------------------------------------------
extern "C" void kernel_launch(void* const* d_in, const int* in_sizes, int n_in,
                              void* d_out, int out_size, void* d_ws, size_t ws_size,
                              hipStream_t stream)
{
    const int*   x     = (const int*)  d_in[0];
    const int*   len   = (const int*)  d_in[1];
    const float* emb   = (const float*)d_in[2];
    const float* W_ih1 = (const float*)d_in[3];
    const float* W_hh1 = (const float*)d_in[4];
    const float* b1    = (const float*)d_in[5];
    const float* W_ih2 = (const float*)d_in[6];
    const float* W_hh2 = (const float*)d_in[7];
    const float* b2    = (const float*)d_in[8];
    const float* fc1w  = (const float*)d_in[9];
    const float* fc1b  = (const float*)d_in[10];
    const float* fc2w  = (const float*)d_in[11];
    const float* fc2b  = (const float*)d_in[12];
    float* out = (float*)d_out;

    const size_t wt_bytes = (size_t)EE * JP * sizeof(float);     // 307200
    const size_t per_b    = (size_t)TT * G4 * sizeof(float);     // 409600
    float* Wt = (float*)d_ws;
    float* G1 = (float*)((char*)d_ws + wt_bytes);

    size_t avail = ws_size > wt_bytes ? ws_size - wt_bytes : 0;
    int chunk = (int)(avail / per_b);
    if (chunk < 1) chunk = 1;
    if (chunk > BB) chunk = BB;

    wtrans_kernel<<<dim3(EE), dim3(256), 0, stream>>>(W_ih1, Wt);

    for (int b0 = 0; b0 < BB; b0 += chunk) {
        int nb = (BB - b0) < chunk ? (BB - b0) : chunk;
        proj_kernel<<<dim3(TT / 64, nb), dim3(256), 0, stream>>>(
            x, len, emb, b1, Wt, G1, b0);
        lstm_kernel<<<dim3(nb), dim3(320), 0, stream>>>(
            len, W_hh1, W_ih2, W_hh2, b2, fc1w, fc1b, fc2w, fc2b, G1, out, b0);
    }
}

// Round 3
// 566.596 us; speedup vs baseline: 1.6125x; 1.2023x over previous
//
#include <hip/hip_runtime.h>
#include <hip/hip_bf16.h>

#define BB 256
#define TT 512
#define EE 300
#define G4 200     // 4*H1
#define JP 256     // padded gate dim for Wt
#define BKP 60     // proj LDS stage depth (300 = 5*60)

// permuted gate col: G1 column jp corresponds to W row (jp&3)*50 + (jp>>2),
// so thread tid==jp in lstm has gates (i,f,g,o) of unit u=tid>>2 in its quad.

__device__ __forceinline__ float sigm(float x) {
    return __builtin_amdgcn_rcpf(1.f + __builtin_amdgcn_exp2f(-1.442695040888963f * x));
}
__device__ __forceinline__ float tanh_(float x) {
    float t = __builtin_amdgcn_exp2f(2.885390081777927f * x);   // e^(2x)
    return 1.f - 2.f * __builtin_amdgcn_rcpf(t + 1.f);
}

// quad broadcast via DPP: lane gets value from (quad base + K) — 1 VALU op
template <int C>
__device__ __forceinline__ float qb(float v) {
    return __int_as_float(__builtin_amdgcn_mov_dpp(__float_as_int(v), C, 0xF, 0xF, true));
}

// ---------------------------------------------------------------------------
// K1: permuted transpose + zero-pad W_ih1 [200,300] -> Wt [300][256]
__global__ void wtrans_kernel(const float* __restrict__ W, float* __restrict__ Wt) {
    int e = blockIdx.x;        // 0..299
    int j = threadIdx.x;       // 0..255
    float v = 0.f;
    if (j < G4) {
        int row = (j & 3) * 50 + (j >> 2);
        v = W[row * EE + e];
    }
    Wt[e * JP + j] = v;
}

// ---------------------------------------------------------------------------
// K2: G1[bb][t][jp] = b1[row(jp)] + emb[x[b][t]] . W_ih1[row(jp)]
// 64 t-rows x 200 cols per block; Wt staged in LDS; thread tile 8 rows x
// (4 cols @ 4*jg + 4 cols @ 100+4*jg).
__device__ __forceinline__ float f4get(const float4& v, int u) {
    return u == 0 ? v.x : u == 1 ? v.y : u == 2 ? v.z : v.w;
}

__global__ __launch_bounds__(256, 2) void proj_kernel(
    const int* __restrict__ x, const int* __restrict__ lengths,
    const float* __restrict__ emb, const float* __restrict__ b1,
    const float* __restrict__ Wt, float* __restrict__ G1, int b0)
{
    const int b  = b0 + blockIdx.y;
    const int t0 = blockIdx.x * 64;
    const int len = lengths[b];
    if (t0 >= len) return;                       // whole tile is padding: dead

    const int tid = threadIdx.x;
    const int rg  = tid >> 5;                    // 0..7 : rows rg*8 .. rg*8+7
    const int jg  = tid & 31;                    // col groups; valid if jg<25
    const bool active = (jg < 25);

    __shared__ float4 Ws4[BKP * 50];             // 48 KB: [k][c4] c4=0..49

    const float* er[8];
    #pragma unroll
    for (int q = 0; q < 8; ++q)
        er[q] = emb + (size_t)x[b * TT + t0 + rg * 8 + q] * EE;

    float acc[8][8];
    {
        float bv[8];
        #pragma unroll
        for (int k = 0; k < 8; ++k) {
            int c = (k < 4) ? (4 * jg + k) : (96 + 4 * jg + k);   // k>=4: 100+4jg+(k-4)
            bv[k] = active ? b1[(c & 3) * 50 + (c >> 2)] : 0.f;
        }
        #pragma unroll
        for (int q = 0; q < 8; ++q)
            #pragma unroll
            for (int k = 0; k < 8; ++k) acc[q][k] = bv[k];
    }

    const float4* Wt4 = (const float4*)Wt;       // [300][64] float4s

    for (int s = 0; s < 5; ++s) {
        const int e0 = s * BKP;
        // ---- stage Wt[e0..e0+59][0..199] into LDS (coalesced)
        for (int i = tid; i < BKP * 50; i += 256) {
            int r = i / 50;
            int c = i - r * 50;
            Ws4[i] = Wt4[(size_t)(e0 + r) * (JP / 4) + c];
        }
        __syncthreads();
        if (active) {
            for (int kk = 0; kk < BKP / 4; ++kk) {
                float4 av[8];
                #pragma unroll
                for (int q = 0; q < 8; ++q)
                    av[q] = *(const float4*)(er[q] + e0 + kk * 4);
                #pragma unroll
                for (int u = 0; u < 4; ++u) {
                    float4 w0 = Ws4[(kk * 4 + u) * 50 + jg];
                    float4 w1 = Ws4[(kk * 4 + u) * 50 + 25 + jg];
                    #pragma unroll
                    for (int q = 0; q < 8; ++q) {
                        float a = f4get(av[q], u);
                        acc[q][0] = fmaf(a, w0.x, acc[q][0]);
                        acc[q][1] = fmaf(a, w0.y, acc[q][1]);
                        acc[q][2] = fmaf(a, w0.z, acc[q][2]);
                        acc[q][3] = fmaf(a, w0.w, acc[q][3]);
                        acc[q][4] = fmaf(a, w1.x, acc[q][4]);
                        acc[q][5] = fmaf(a, w1.y, acc[q][5]);
                        acc[q][6] = fmaf(a, w1.z, acc[q][6]);
                        acc[q][7] = fmaf(a, w1.w, acc[q][7]);
                    }
                }
            }
        }
        __syncthreads();
    }

    if (active) {
        float* gbase = G1 + ((size_t)blockIdx.y * TT + t0) * G4;
        #pragma unroll
        for (int q = 0; q < 8; ++q) {
            float* gp = gbase + (size_t)(rg * 8 + q) * G4;
            *(float4*)(gp + 4 * jg)       = make_float4(acc[q][0], acc[q][1], acc[q][2], acc[q][3]);
            *(float4*)(gp + 100 + 4 * jg) = make_float4(acc[q][4], acc[q][5], acc[q][6], acc[q][7]);
        }
    }
}

// ---------------------------------------------------------------------------
// K3: recurrence. One block (320 thr) per batch element, 1 barrier per step.
// tid 0..199   : LSTM1 row (tid&3)*50+(tid>>2)  (waves 0..3, quad = unit)
// tid 256..295 : LSTM2 row (q&3)*10+(q>>2), q=tid-256 (wave 4), lags 1 step
__global__ __launch_bounds__(320, 1) void lstm_kernel(
    const int* __restrict__ lengths,
    const float* __restrict__ W_hh1, const float* __restrict__ W_ih2,
    const float* __restrict__ W_hh2, const float* __restrict__ b2,
    const float* __restrict__ fc1w, const float* __restrict__ fc1b,
    const float* __restrict__ fc2w, const float* __restrict__ fc2b,
    const float* __restrict__ G1, float* __restrict__ out, int b0)
{
    const int bb  = blockIdx.x;
    const int b   = b0 + bb;
    const int tid = threadIdx.x;
    const int len = lengths[b];

    __shared__ __align__(16) float h1s[2][52];
    __shared__ __align__(16) float h2s[2][12];
    __shared__ __align__(16) float hfin[12];
    __shared__ float zbuf[10];

    if (tid < 52) { h1s[0][tid] = 0.f; h1s[1][tid] = 0.f; }
    if (tid < 12) { h2s[0][tid] = 0.f; h2s[1][tid] = 0.f; }

    const bool is1 = (tid < 200);
    const bool is2 = (tid >= 256 && tid < 296);

    float wreg[52];                 // LSTM1: W_hh1 row | LSTM2: W_ih2 row
    float wregb[12];                // LSTM2: W_hh2 row
    #pragma unroll
    for (int k = 0; k < 52; ++k) wreg[k] = 0.f;
    #pragma unroll
    for (int k = 0; k < 12; ++k) wregb[k] = 0.f;
    float b2r = 0.f;

    if (is1) {
        int u = tid >> 2, g = tid & 3;
        const float* wp = W_hh1 + (g * 50 + u) * 50;
        #pragma unroll
        for (int k = 0; k < 50; ++k) wreg[k] = wp[k];
    } else if (is2) {
        int q = tid - 256, u = q >> 2, g = q & 3;
        int row = g * 10 + u;
        const float* wp = W_ih2 + row * 50;
        #pragma unroll
        for (int k = 0; k < 50; ++k) wreg[k] = wp[k];
        const float* wp2 = W_hh2 + row * 10;
        #pragma unroll
        for (int k = 0; k < 10; ++k) wregb[k] = wp2[k];
        b2r = b2[row];
    }
    // pin weights into VGPRs: forbid rematerialization-from-global per step
    #pragma unroll
    for (int k = 0; k < 52; ++k) asm volatile("" : "+v"(wreg[k]));
    #pragma unroll
    for (int k = 0; k < 12; ++k) asm volatile("" : "+v"(wregb[k]));
    asm volatile("" : "+v"(b2r));

    float h1v[52], h2v[12];
    #pragma unroll
    for (int k = 0; k < 52; ++k) h1v[k] = 0.f;
    #pragma unroll
    for (int k = 0; k < 12; ++k) h2v[k] = 0.f;

    float c1 = 0.f, c2 = 0.f;
    const float* g1p = G1 + (size_t)bb * TT * G4;
    float g0 = 0.f, g1r = 0.f;
    if (is1) {
        g0 = g1p[tid];                               // row t=0
        int t1 = (1 < len) ? 1 : 0;
        g1r = g1p[(size_t)t1 * G4 + tid];            // row t=1
    }

    __syncthreads();                                 // LDS zero-init visible

    for (int i = 0; i < len; ++i) {
        if (is1) {
            float g = g0;
            g0 = g1r;
            int tn = (i + 2 < len) ? i + 2 : len - 1;
            g1r = g1p[(size_t)tn * G4 + tid];         // prefetch 2 ahead
            float s0 = 0.f, s1 = 0.f, s2 = 0.f, s3 = 0.f;
            #pragma unroll
            for (int m = 0; m < 13; ++m) {
                s0 = fmaf(wreg[4*m+0], h1v[4*m+0], s0);
                s1 = fmaf(wreg[4*m+1], h1v[4*m+1], s1);
                s2 = fmaf(wreg[4*m+2], h1v[4*m+2], s2);
                s3 = fmaf(wreg[4*m+3], h1v[4*m+3], s3);
            }
            float gv = g + (s0 + s1) + (s2 + s3);
            float gi = qb<0x00>(gv);
            float gf = qb<0x55>(gv);
            float gg = qb<0xAA>(gv);
            float go = qb<0xFF>(gv);
            float cn = sigm(gf) * c1 + sigm(gi) * tanh_(gg);
            c1 = cn;
            float hn = sigm(go) * tanh_(cn);
            if ((tid & 3) == 0) h1s[i & 1][tid >> 2] = hn;
        } else if (is2 && i >= 1) {
            float s0 = 0.f, s1 = 0.f, s2 = 0.f, s3 = 0.f;
            #pragma unroll
            for (int m = 0; m < 13; ++m) {
                s0 = fmaf(wreg[4*m+0], h1v[4*m+0], s0);
                s1 = fmaf(wreg[4*m+1], h1v[4*m+1], s1);
                s2 = fmaf(wreg[4*m+2], h1v[4*m+2], s2);
                s3 = fmaf(wreg[4*m+3], h1v[4*m+3], s3);
            }
            #pragma unroll
            for (int m = 0; m < 3; ++m) {
                s0 = fmaf(wregb[4*m+0], h2v[4*m+0], s0);
                s1 = fmaf(wregb[4*m+1], h2v[4*m+1], s1);
                s2 = fmaf(wregb[4*m+2], h2v[4*m+2], s2);
                s3 = fmaf(wregb[4*m+3], h2v[4*m+3], s3);
            }
            float gv = b2r + (s0 + s1) + (s2 + s3);
            float gi = qb<0x00>(gv);
            float gf = qb<0x55>(gv);
            float gg = qb<0xAA>(gv);
            float go = qb<0xFF>(gv);
            float cn = sigm(gf) * c2 + sigm(gi) * tanh_(gg);
            c2 = cn;
            float hn = sigm(go) * tanh_(cn);
            if ((tid & 3) == 0) h2s[i & 1][(tid - 256) >> 2] = hn;
        }
        __syncthreads();
        // reload h(i) into regs from the buffer written this iteration
        {
            const float* hb = h1s[i & 1];
            #pragma unroll
            for (int m = 0; m < 13; ++m) {
                float4 v = *(const float4*)(hb + 4 * m);
                h1v[4*m+0] = v.x; h1v[4*m+1] = v.y;
                h1v[4*m+2] = v.z; h1v[4*m+3] = v.w;
            }
            if (tid >= 256) {                         // wave-uniform guard
                const float* hb2 = h2s[i & 1];
                #pragma unroll
                for (int m = 0; m < 3; ++m) {
                    float4 v = *(const float4*)(hb2 + 4 * m);
                    h2v[4*m+0] = v.x; h2v[4*m+1] = v.y;
                    h2v[4*m+2] = v.z; h2v[4*m+3] = v.w;
                }
            }
        }
    }

    // ---- tail: h2(len-1) from h1(len-1), h2(len-2)
    if (is2) {
        float s0 = 0.f, s1 = 0.f, s2 = 0.f, s3 = 0.f;
        #pragma unroll
        for (int m = 0; m < 13; ++m) {
            s0 = fmaf(wreg[4*m+0], h1v[4*m+0], s0);
            s1 = fmaf(wreg[4*m+1], h1v[4*m+1], s1);
            s2 = fmaf(wreg[4*m+2], h1v[4*m+2], s2);
            s3 = fmaf(wreg[4*m+3], h1v[4*m+3], s3);
        }
        #pragma unroll
        for (int m = 0; m < 3; ++m) {
            s0 = fmaf(wregb[4*m+0], h2v[4*m+0], s0);
            s1 = fmaf(wregb[4*m+1], h2v[4*m+1], s1);
            s2 = fmaf(wregb[4*m+2], h2v[4*m+2], s2);
            s3 = fmaf(wregb[4*m+3], h2v[4*m+3], s3);
        }
        float gv = b2r + (s0 + s1) + (s2 + s3);
        float gi = qb<0x00>(gv);
        float gf = qb<0x55>(gv);
        float gg = qb<0xAA>(gv);
        float go = qb<0xFF>(gv);
        float cn = sigm(gf) * c2 + sigm(gi) * tanh_(gg);
        float hn = sigm(go) * tanh_(cn);
        if ((tid & 3) == 0) hfin[(tid - 256) >> 2] = hn;
    }
    __syncthreads();

    // ---- MLP head
    if (tid < 10) {
        float s = fc1b[tid];
        #pragma unroll
        for (int e = 0; e < 10; ++e) s = fmaf(fc1w[tid * 10 + e], hfin[e], s);
        zbuf[tid] = s > 0.f ? s : 0.f;
    }
    __syncthreads();
    if (tid == 0) {
        float s = fc2b[0];
        #pragma unroll
        for (int e = 0; e < 10; ++e) s = fmaf(fc2w[e], zbuf[e], s);
        out[b] = s;
    }
}

// ---------------------------------------------------------------------------
extern "C" void kernel_launch(void* const* d_in, const int* in_sizes, int n_in,
                              void* d_out, int out_size, void* d_ws, size_t ws_size,
                              hipStream_t stream)
{
    const int*   x     = (const int*)  d_in[0];
    const int*   len   = (const int*)  d_in[1];
    const float* emb   = (const float*)d_in[2];
    const float* W_ih1 = (const float*)d_in[3];
    const float* W_hh1 = (const float*)d_in[4];
    const float* b1    = (const float*)d_in[5];
    const float* W_ih2 = (const float*)d_in[6];
    const float* W_hh2 = (const float*)d_in[7];
    const float* b2    = (const float*)d_in[8];
    const float* fc1w  = (const float*)d_in[9];
    const float* fc1b  = (const float*)d_in[10];
    const float* fc2w  = (const float*)d_in[11];
    const float* fc2b  = (const float*)d_in[12];
    float* out = (float*)d_out;

    const size_t wt_bytes = (size_t)EE * JP * sizeof(float);     // 307200
    const size_t per_b    = (size_t)TT * G4 * sizeof(float);     // 409600
    float* Wt = (float*)d_ws;
    float* G1 = (float*)((char*)d_ws + wt_bytes);

    size_t avail = ws_size > wt_bytes ? ws_size - wt_bytes : 0;
    int chunk = (int)(avail / per_b);
    if (chunk < 1) chunk = 1;
    if (chunk > BB) chunk = BB;

    wtrans_kernel<<<dim3(EE), dim3(256), 0, stream>>>(W_ih1, Wt);

    for (int b0 = 0; b0 < BB; b0 += chunk) {
        int nb = (BB - b0) < chunk ? (BB - b0) : chunk;
        proj_kernel<<<dim3(TT / 64, nb), dim3(256), 0, stream>>>(
            x, len, emb, b1, Wt, G1, b0);
        lstm_kernel<<<dim3(nb), dim3(320), 0, stream>>>(
            len, W_hh1, W_ih2, W_hh2, b2, fc1w, fc1b, fc2w, fc2b, G1, out, b0);
    }
}